// Round 5
// baseline (563.131 us; speedup 1.0000x reference)
//
#include <hip/hip_runtime.h>

#define BTOT 1048576
#define D 17
#define H 8
#define OUT 6
#define E 4
#define G1 64
#define G2 32
#define CHUNKS 4
#define XSTR 17   // sxp row stride in dwords (no pad; weight k>=17 zeroed instead)
#define GTHR 5.0e-3f

typedef float f32x4 __attribute__((ext_vector_type(4)));
typedef float f32x2 __attribute__((ext_vector_type(2)));
typedef short s16x8 __attribute__((ext_vector_type(8)));
typedef unsigned int uint;
typedef unsigned short ushort_t;

union U4S8 { uint u[4]; s16x8 s; };

// round fp32 bits to bf16 (RNE), return fp32 bit pattern (low 16 zeroed)
__device__ __forceinline__ uint bfr(uint u) {
    return (u + 0x7fffu + ((u >> 16) & 1u)) & 0xffff0000u;
}

// weight RNE 2-way split (done once at stage): v ~= h + l, err <= 2^-18|v|
__device__ __forceinline__ void wsplit(float v, uint &h, uint &l) {
    uint hb = bfr(__float_as_uint(v));
    float r = v - __uint_as_float(hb);
    h = hb >> 16;
    l = bfr(__float_as_uint(r)) >> 16;
}

// activation trunc 3-way split of 8 values (ascending k), perm-packed:
// v = h + m + l + delta, |m|<=2^-7|v|, |l|<=2^-14|v|, |delta|<=2^-21|v|
__device__ __forceinline__ void split8t(const float* p, s16x8 &fh, s16x8 &fm, s16x8 &fl) {
    U4S8 Hh, Mm, Ll;
    #pragma unroll
    for (int i = 0; i < 4; ++i) {
        float a = p[2 * i], b = p[2 * i + 1];
        uint ua = __float_as_uint(a), ub = __float_as_uint(b);
        Hh.u[i] = __builtin_amdgcn_perm(ub, ua, 0x07060302u);   // [a.hi16 | b.hi16<<16]
        float ra = a - __uint_as_float(ua & 0xffff0000u);       // exact
        float rb = b - __uint_as_float(ub & 0xffff0000u);
        uint ura = __float_as_uint(ra), urb = __float_as_uint(rb);
        Mm.u[i] = __builtin_amdgcn_perm(urb, ura, 0x07060302u);
        float sa = ra - __uint_as_float(ura & 0xffff0000u);     // exact
        float sb = rb - __uint_as_float(urb & 0xffff0000u);
        Ll.u[i] = __builtin_amdgcn_perm(__float_as_uint(sb), __float_as_uint(sa), 0x07060302u);
    }
    fh = Hh.s; fm = Mm.s; fl = Ll.s;
}

// 5-term MFMA product: D += (ah+am+al)*(bh+bl), ascending magnitude order.
// dropped: al*bl (2^-23), deltas (<=2^-18) -> logit err ~1e-5 typ, <=1.5e-4 worst
#define MM5(dacc, ah, am, al, bh, bl)                                            \
    dacc = __builtin_amdgcn_mfma_f32_16x16x32_bf16(am, bl, dacc, 0, 0, 0);       \
    dacc = __builtin_amdgcn_mfma_f32_16x16x32_bf16(al, bh, dacc, 0, 0, 0);       \
    dacc = __builtin_amdgcn_mfma_f32_16x16x32_bf16(ah, bl, dacc, 0, 0, 0);       \
    dacc = __builtin_amdgcn_mfma_f32_16x16x32_bf16(am, bh, dacc, 0, 0, 0);       \
    dacc = __builtin_amdgcn_mfma_f32_16x16x32_bf16(ah, bh, dacc, 0, 0, 0);

#define WSTR 292  // expert blocks start on bank quads {0,4,8,12}: sel-gathers disjoint

__global__ __launch_bounds__(256, 3) void hybrid_ruc_kernel(
    const float* __restrict__ x,
    const float* __restrict__ eW1, const float* __restrict__ eb1,
    const float* __restrict__ eW2, const float* __restrict__ eb2,
    const float* __restrict__ eW3, const float* __restrict__ eb3,
    const float* __restrict__ gW1, const float* __restrict__ gb1,
    const float* __restrict__ gW2, const float* __restrict__ gb2,
    const float* __restrict__ gW3, const float* __restrict__ gb3,
    float* __restrict__ out)
{
    // ---- LDS: 17472 + 6144 + 9216 + 512 + 16384 + 4736-64 = 54464 B (3 blocks/CU) ----
    __shared__ __align__(16) float    sxp[256 * XSTR + 16]; // x fp32, 16-dw zeroed tail
    __shared__ __align__(16) ushort_t sW1h[64 * 24];        // W1^T [n][k<24] bf16 hi (k>=17 = 0)
    __shared__ __align__(16) ushort_t sW1l[64 * 24];        // W1^T lo
    __shared__ __align__(16) ushort_t sW2h[32 * 72];        // W2^T [n][k<64], stride 72
    __shared__ __align__(16) ushort_t sW2l[32 * 72];
    __shared__ __align__(16) ushort_t sW3h[4 * 32];         // W3^T [n][k<32]
    __shared__ __align__(16) ushort_t sW3l[4 * 32];
    __shared__ __align__(16) float    sscr[4][1024];        // per-wave scratch (h1/h2/logits/fallback)
    __shared__ __align__(16) float    swl[E * WSTR];        // expert weights (R1 layout)

    const int tid = threadIdx.x;
    const int wv  = tid >> 6;
    const int ln  = tid & 63;
    const int g   = ln >> 4;   // k-block group for MFMA fragments
    const int nn  = ln & 15;   // row (A) / col (B,D) within 16-tile
    float* scr = sscr[wv];

    // ======== one-time staging ========
    if (tid < 16) sxp[256 * XSTR + tid] = 0.0f;            // NaN-proof tail pad
    for (int t = tid; t < 64 * 24; t += 256) {             // gating W1^T
        int n = t / 24, k = t % 24;
        float v = (k < D) ? gW1[k * G1 + n] : 0.0f;
        uint h, l; wsplit(v, h, l);
        sW1h[t] = (ushort_t)h; sW1l[t] = (ushort_t)l;
    }
    for (int t = tid; t < 32 * 64; t += 256) {             // gating W2^T
        int n = t >> 6, k = t & 63;
        uint h, l; wsplit(gW2[k * G2 + n], h, l);
        int a = n * 72 + k;
        sW2h[a] = (ushort_t)h; sW2l[a] = (ushort_t)l;
    }
    if (tid < 4 * 32) {                                    // gating W3^T
        int n = tid >> 5, k = tid & 31;
        uint h, l; wsplit(gW3[k * E + n], h, l);
        sW3h[tid] = (ushort_t)h; sW3l[tid] = (ushort_t)l;
        (void)n; (void)k;
    }
    // expert weights (R1 bank-quad layout, stride 292)
    for (int t = tid; t < E * D * H; t += 256) {           // eW1: 544
        swl[(t / 136) * WSTR + (t % 136)] = eW1[t];
    }
    if (tid < E * H * H) {                                  // eW2: 256
        swl[(tid / 64) * WSTR + 144 + (tid % 64)] = eW2[tid];
    }
    if (tid < E * H * OUT) {                                // eW3: 192, rows padded to 8
        int e = tid / 48, r = tid % 48, k = r / 6, o = r % 6;
        swl[e * WSTR + 216 + k * 8 + o] = eW3[tid];
    }
    if (tid < E * H) swl[(tid / 8) * WSTR + 136 + (tid % 8)] = eb1[tid];
    if (tid < E * H) swl[(tid / 8) * WSTR + 208 + (tid % 8)] = eb2[tid];
    if (tid < E * OUT) swl[(tid / 6) * WSTR + 280 + (tid % 6)] = eb3[tid];
    __syncthreads();

    // ======== hoist gating biases + B-fragments (2 kinds) ========
    float cb1[4], cb2[2], cb3;
    #pragma unroll
    for (int ct = 0; ct < 4; ++ct) cb1[ct] = gb1[ct * 16 + nn];
    cb2[0] = gb2[nn]; cb2[1] = gb2[16 + nn];
    cb3 = (nn < 4) ? gb3[nn] : 0.0f;

    const s16x8 z8 = {0, 0, 0, 0, 0, 0, 0, 0};
    s16x8 B1h[4], B1l[4];
    #pragma unroll
    for (int ct = 0; ct < 4; ++ct) {
        B1h[ct] = (g <= 2) ? *(const s16x8*)(&sW1h[(ct * 16 + nn) * 24 + g * 8]) : z8;
        B1l[ct] = (g <= 2) ? *(const s16x8*)(&sW1l[(ct * 16 + nn) * 24 + g * 8]) : z8;
    }
    s16x8 B2h[2][2], B2l[2][2];
    #pragma unroll
    for (int ct = 0; ct < 2; ++ct)
        #pragma unroll
        for (int kt = 0; kt < 2; ++kt) {
            B2h[ct][kt] = *(const s16x8*)(&sW2h[(ct * 16 + nn) * 72 + kt * 32 + g * 8]);
            B2l[ct][kt] = *(const s16x8*)(&sW2l[(ct * 16 + nn) * 72 + kt * 32 + g * 8]);
        }
    s16x8 B3h = (nn < 4) ? *(const s16x8*)(&sW3h[nn * 32 + g * 8]) : z8;
    s16x8 B3l = (nn < 4) ? *(const s16x8*)(&sW3l[nn * 32 + g * 8]) : z8;

    // ======== chunk loop: 4 chunks of 256 samples ========
    #pragma unroll 1
    for (int c = 0; c < CHUNKS; ++c) {
        if (c) __syncthreads();
        const long long cbase = ((long long)blockIdx.x * CHUNKS + c) * 256;

        // stage x chunk: linear coalesced copy (XSTR == D)
        #pragma unroll
        for (int k = 0; k < D; ++k) {
            int t = tid + k * 256;
            sxp[t] = x[cbase * D + t];
        }
        __syncthreads();

        // ---- gating via MFMA (per-wave: 4 row-tiles of 16 samples) ----
        f32x4 Lg[4];
        #pragma unroll
        for (int rt = 0; rt < 4; ++rt) {
            const int srow = wv * 64 + rt * 16 + nn;
            // A1: 8 fp32 (k = g*8..g*8+7); tails past k=16 are garbage from the
            // next row — inert because sW1 k>=17 planes are zero.
            float xv[8];
            const int xb = srow * XSTR + g * 8;
            #pragma unroll
            for (int j = 0; j < 8; ++j) xv[j] = sxp[xb + j];
            s16x8 a1h, a1m, a1l; split8t(xv, a1h, a1m, a1l);

            // L1: 17->64, 4 col-tiles
            #pragma unroll
            for (int ct = 0; ct < 4; ++ct) {
                f32x4 d = {cb1[ct], cb1[ct], cb1[ct], cb1[ct]};
                MM5(d, a1h, a1m, a1l, B1h[ct], B1l[ct]);
                #pragma unroll
                for (int r = 0; r < 4; ++r) {
                    float hv = fmaxf(d[r], 0.0f);
                    int s = g * 4 + r, n = ct * 16 + nn;
                    scr[s * 64 + (((n >> 2) ^ (s & 15)) << 2) + (n & 3)] = hv;
                }
            }

            // A2 frags from h1
            s16x8 a2h[2], a2m[2], a2l[2];
            #pragma unroll
            for (int kt = 0; kt < 2; ++kt) {
                int kb0 = kt * 8 + g * 2;
                float hv8[8];
                *(f32x4*)&hv8[0] = *(const f32x4*)(&scr[nn * 64 + ((kb0 ^ (nn & 15)) << 2)]);
                *(f32x4*)&hv8[4] = *(const f32x4*)(&scr[nn * 64 + (((kb0 + 1) ^ (nn & 15)) << 2)]);
                split8t(hv8, a2h[kt], a2m[kt], a2l[kt]);
            }

            // L2: 64->32
            #pragma unroll
            for (int ct = 0; ct < 2; ++ct) {
                f32x4 d = {cb2[ct], cb2[ct], cb2[ct], cb2[ct]};
                #pragma unroll
                for (int kt = 0; kt < 2; ++kt) {
                    MM5(d, a2h[kt], a2m[kt], a2l[kt], B2h[ct][kt], B2l[ct][kt]);
                }
                #pragma unroll
                for (int r = 0; r < 4; ++r) {
                    float hv = fmaxf(d[r], 0.0f);
                    int s = g * 4 + r, n = ct * 16 + nn;
                    scr[s * 32 + (((n >> 2) ^ (s & 7)) << 2) + (n & 3)] = hv;
                }
            }

            // A3 frags from h2
            float h28[8];
            *(f32x4*)&h28[0] = *(const f32x4*)(&scr[nn * 32 + (((2 * g) ^ (nn & 7)) << 2)]);
            *(f32x4*)&h28[4] = *(const f32x4*)(&scr[nn * 32 + (((2 * g + 1) ^ (nn & 7)) << 2)]);
            s16x8 a3h, a3m, a3l; split8t(h28, a3h, a3m, a3l);

            // L3: 32->4
            f32x4 d3 = {cb3, cb3, cb3, cb3};
            MM5(d3, a3h, a3m, a3l, B3h, B3l);
            Lg[rt] = d3;
        }

        // ---- redistribute logits: D-layout -> one sample per lane ----
        if (nn < 4) {
            #pragma unroll
            for (int rt = 0; rt < 4; ++rt)
                #pragma unroll
                for (int r = 0; r < 4; ++r)
                    scr[(rt * 16 + g * 4 + r) * 4 + nn] = Lg[rt][r];
        }
        f32x4 lgv = *(const f32x4*)(&scr[ln * 4]);

        // ---- argmax (first-max-wins) + top-2 gap ----
        int sel = 0;
        {
            float b = lgv.x;
            if (lgv.y > b) { b = lgv.y; sel = 1; }
            if (lgv.z > b) { b = lgv.z; sel = 2; }
            if (lgv.w > b) { b = lgv.w; sel = 3; }
        }
        float mx01 = fmaxf(lgv.x, lgv.y), mn01 = fminf(lgv.x, lgv.y);
        float mx23 = fmaxf(lgv.z, lgv.w), mn23 = fminf(lgv.z, lgv.w);
        float best   = fmaxf(mx01, mx23);
        float second = fmaxf(fminf(mx01, mx23), (mx01 >= mx23) ? mn01 : mn23);

        // ---- rare exact-fp32 cooperative fallback for near-tie routing ----
        unsigned long long fmask = __ballot(best - second < GTHR);
        if (fmask) {
            do {
                int sl = (int)__builtin_ctzll(fmask);
                fmask &= (fmask - 1);
                const int fr = wv * 64 + sl;           // flagged sample's sxp row
                // L1: lane j computes h1_j exactly (x broadcast from LDS)
                float h1j = gb1[ln];
                #pragma unroll 1
                for (int i = 0; i < D; ++i)
                    h1j = __builtin_fmaf(sxp[fr * XSTR + i], gW1[i * G1 + ln], h1j);
                scr[ln] = fmaxf(h1j, 0.0f);
                // L2: lane j&31 computes h2 (lanes 32-63 duplicate)
                int j2 = ln & 31;
                float h2j = gb2[j2];
                #pragma unroll 4
                for (int c2 = 0; c2 < G1; ++c2)
                    h2j = __builtin_fmaf(scr[c2], gW2[c2 * G2 + j2], h2j);
                scr[64 + j2] = fmaxf(h2j, 0.0f);
                // L3: lane j&3 computes logit e (duplicated x16)
                int e = ln & 3;
                float lge = gb3[e];
                #pragma unroll 4
                for (int jj = 0; jj < G2; ++jj)
                    lge = __builtin_fmaf(scr[64 + jj], gW3[jj * E + e], lge);
                float l0 = __shfl(lge, 0), l1 = __shfl(lge, 1);
                float l2 = __shfl(lge, 2), l3 = __shfl(lge, 3);
                int s2 = 0; float bb = l0;
                if (l1 > bb) { bb = l1; s2 = 1; }
                if (l2 > bb) { bb = l2; s2 = 2; }
                if (l3 > bb) { bb = l3; s2 = 3; }
                if (ln == sl) sel = s2;
            } while (fmask);
        }

        // ---- selected expert only (R1 path) ----
        float xr[D];
        {
            const float* xrow = &sxp[tid * XSTR];
            #pragma unroll
            for (int i = 0; i < D; ++i) xr[i] = xrow[i];
        }
        const float* wl = &swl[sel * WSTR];

        float t1[H];
        {
            f32x4 ba = *(const f32x4*)(wl + 136);
            f32x4 bb = *(const f32x4*)(wl + 140);
            t1[0]=ba.x; t1[1]=ba.y; t1[2]=ba.z; t1[3]=ba.w;
            t1[4]=bb.x; t1[5]=bb.y; t1[6]=bb.z; t1[7]=bb.w;
        }
        #pragma unroll
        for (int i = 0; i < D; ++i) {
            const float xi = xr[i];
            f32x4 wa = *(const f32x4*)(wl + i * 8);
            f32x4 wb = *(const f32x4*)(wl + i * 8 + 4);
            t1[0] = __builtin_fmaf(xi, wa.x, t1[0]);
            t1[1] = __builtin_fmaf(xi, wa.y, t1[1]);
            t1[2] = __builtin_fmaf(xi, wa.z, t1[2]);
            t1[3] = __builtin_fmaf(xi, wa.w, t1[3]);
            t1[4] = __builtin_fmaf(xi, wb.x, t1[4]);
            t1[5] = __builtin_fmaf(xi, wb.y, t1[5]);
            t1[6] = __builtin_fmaf(xi, wb.z, t1[6]);
            t1[7] = __builtin_fmaf(xi, wb.w, t1[7]);
        }
        float t2[H];
        {
            f32x4 ba = *(const f32x4*)(wl + 208);
            f32x4 bb = *(const f32x4*)(wl + 212);
            t2[0]=ba.x; t2[1]=ba.y; t2[2]=ba.z; t2[3]=ba.w;
            t2[4]=bb.x; t2[5]=bb.y; t2[6]=bb.z; t2[7]=bb.w;
        }
        #pragma unroll
        for (int k = 0; k < H; ++k) {
            const float tv = fmaxf(t1[k], 0.0f);
            f32x4 wa = *(const f32x4*)(wl + 144 + k * 8);
            f32x4 wb = *(const f32x4*)(wl + 144 + k * 8 + 4);
            t2[0] = __builtin_fmaf(tv, wa.x, t2[0]);
            t2[1] = __builtin_fmaf(tv, wa.y, t2[1]);
            t2[2] = __builtin_fmaf(tv, wa.z, t2[2]);
            t2[3] = __builtin_fmaf(tv, wa.w, t2[3]);
            t2[4] = __builtin_fmaf(tv, wb.x, t2[4]);
            t2[5] = __builtin_fmaf(tv, wb.y, t2[5]);
            t2[6] = __builtin_fmaf(tv, wb.z, t2[6]);
            t2[7] = __builtin_fmaf(tv, wb.w, t2[7]);
        }
        float pred[OUT];
        {
            f32x4 ba = *(const f32x4*)(wl + 280);
            pred[0]=ba.x; pred[1]=ba.y; pred[2]=ba.z; pred[3]=ba.w;
            pred[4]=wl[284]; pred[5]=wl[285];
        }
        #pragma unroll
        for (int k = 0; k < H; ++k) {
            const float tv = fmaxf(t2[k], 0.0f);
            f32x4 wa = *(const f32x4*)(wl + 216 + k * 8);
            f32x2 wb = *(const f32x2*)(wl + 216 + k * 8 + 4);
            pred[0] = __builtin_fmaf(tv, wa.x, pred[0]);
            pred[1] = __builtin_fmaf(tv, wa.y, pred[1]);
            pred[2] = __builtin_fmaf(tv, wa.z, pred[2]);
            pred[3] = __builtin_fmaf(tv, wa.w, pred[3]);
            pred[4] = __builtin_fmaf(tv, wb.x, pred[4]);
            pred[5] = __builtin_fmaf(tv, wb.y, pred[5]);
        }

        // ---- stores ----
        const long long b = cbase + tid;
        f32x2 p0 = {pred[0], pred[1]};
        f32x2 p1 = {pred[2], pred[3]};
        f32x2 p2 = {pred[4], pred[5]};
        *(f32x2*)(out + b * 6)     = p0;
        *(f32x2*)(out + b * 6 + 2) = p1;
        *(f32x2*)(out + b * 6 + 4) = p2;
        float* lout = out + (long long)BTOT * OUT;
        *(f32x4*)(lout + b * 4) = lgv;
    }
}

extern "C" void kernel_launch(void* const* d_in, const int* in_sizes, int n_in,
                              void* d_out, int out_size, void* d_ws, size_t ws_size,
                              hipStream_t stream) {
    const float* x   = (const float*)d_in[0];
    const float* eW1 = (const float*)d_in[1];
    const float* eb1 = (const float*)d_in[2];
    const float* eW2 = (const float*)d_in[3];
    const float* eb2 = (const float*)d_in[4];
    const float* eW3 = (const float*)d_in[5];
    const float* eb3 = (const float*)d_in[6];
    const float* gW1 = (const float*)d_in[7];
    const float* gb1 = (const float*)d_in[8];
    const float* gW2 = (const float*)d_in[9];
    const float* gb2 = (const float*)d_in[10];
    const float* gW3 = (const float*)d_in[11];
    const float* gb3 = (const float*)d_in[12];
    float* out = (float*)d_out;

    dim3 grid(BTOT / (256 * CHUNKS)), block(256);
    hipLaunchKernelGGL(hybrid_ruc_kernel, grid, block, 0, stream,
                       x, eW1, eb1, eW2, eb2, eW3, eb3,
                       gW1, gb1, gW2, gb2, gW3, gb3, out);
}

// Round 6
// 240.720 us; speedup vs baseline: 2.3394x; 2.3394x over previous
//
#include <hip/hip_runtime.h>

#define BTOT 1048576
#define D 17
#define H 8
#define OUT 6
#define E 4
#define G1 64
#define G2 32
#define CHUNKS 4
#define XSTR 17
#define GTHR 5.0e-3f

typedef float f32x4 __attribute__((ext_vector_type(4)));
typedef float f32x2 __attribute__((ext_vector_type(2)));
typedef short s16x8 __attribute__((ext_vector_type(8)));
typedef unsigned int uint;

union U4S8 { uint u[4]; s16x8 s; };

// round fp32 bits to bf16 (RNE), return fp32 bit pattern (low 16 zeroed)
__device__ __forceinline__ uint bfr(uint u) {
    return (u + 0x7fffu + ((u >> 16) & 1u)) & 0xffff0000u;
}

// RNE 2-way weight split of a pair -> packed bf16x2 words (a in low, b in high)
// v ~= h + l, err <= 2^-18 |v|
__device__ __forceinline__ void wsplit2(float a, float b, uint &hp, uint &lp) {
    uint ha = bfr(__float_as_uint(a));
    uint hb = bfr(__float_as_uint(b));
    float ra = a - __uint_as_float(ha);
    float rb = b - __uint_as_float(hb);
    hp = (ha >> 16) | (hb & 0xffff0000u);
    lp = (bfr(__float_as_uint(ra)) >> 16) | (bfr(__float_as_uint(rb)) & 0xffff0000u);
}

// activation trunc 3-way split of 8 values (ascending k), perm-packed:
// v = h + m + l + delta, |delta| <= 2^-21 |v|
__device__ __forceinline__ void split8t(const float* p, s16x8 &fh, s16x8 &fm, s16x8 &fl) {
    U4S8 Hh, Mm, Ll;
    #pragma unroll
    for (int i = 0; i < 4; ++i) {
        float a = p[2 * i], b = p[2 * i + 1];
        uint ua = __float_as_uint(a), ub = __float_as_uint(b);
        Hh.u[i] = __builtin_amdgcn_perm(ub, ua, 0x07060302u);   // [a.hi16 | b.hi16<<16]
        float ra = a - __uint_as_float(ua & 0xffff0000u);       // exact
        float rb = b - __uint_as_float(ub & 0xffff0000u);
        uint ura = __float_as_uint(ra), urb = __float_as_uint(rb);
        Mm.u[i] = __builtin_amdgcn_perm(urb, ura, 0x07060302u);
        float sa = ra - __uint_as_float(ura & 0xffff0000u);     // exact
        float sb = rb - __uint_as_float(urb & 0xffff0000u);
        Ll.u[i] = __builtin_amdgcn_perm(__float_as_uint(sb), __float_as_uint(sa), 0x07060302u);
    }
    fh = Hh.s; fm = Mm.s; fl = Ll.s;
}

// 5-term MFMA product: D += (ah+am+al)*(bh+bl), ascending magnitude order.
#define MM5(dacc, ah, am, al, bh, bl)                                            \
    dacc = __builtin_amdgcn_mfma_f32_16x16x32_bf16(am, bl, dacc, 0, 0, 0);       \
    dacc = __builtin_amdgcn_mfma_f32_16x16x32_bf16(al, bh, dacc, 0, 0, 0);       \
    dacc = __builtin_amdgcn_mfma_f32_16x16x32_bf16(ah, bl, dacc, 0, 0, 0);       \
    dacc = __builtin_amdgcn_mfma_f32_16x16x32_bf16(am, bh, dacc, 0, 0, 0);       \
    dacc = __builtin_amdgcn_mfma_f32_16x16x32_bf16(ah, bh, dacc, 0, 0, 0);

#define WSTR 292  // expert blocks start on bank quads {0,4,8,12}: sel-gathers disjoint

__global__ __launch_bounds__(256, 2) void hybrid_ruc_kernel(
    const float* __restrict__ x,
    const float* __restrict__ eW1, const float* __restrict__ eb1,
    const float* __restrict__ eW2, const float* __restrict__ eb2,
    const float* __restrict__ eW3, const float* __restrict__ eb3,
    const float* __restrict__ gW1, const float* __restrict__ gb1,
    const float* __restrict__ gW2, const float* __restrict__ gb2,
    const float* __restrict__ gW3, const float* __restrict__ gb3,
    float* __restrict__ out)
{
    // ---- LDS: 17472 + 16384 + 4672 = 38528 B -> 4 blocks/CU ----
    __shared__ __align__(16) float sscr[4][1024];         // per-wave scratch (h1/h2/logits/fallback)
    __shared__ __align__(16) float swl[E * WSTR];         // expert weights
    __shared__ __align__(16) float sxp[256 * XSTR + 16];  // x fp32 + zeroed tail

    const int tid = threadIdx.x;
    const int wv  = tid >> 6;
    const int ln  = tid & 63;
    const int g   = ln >> 4;   // k-block group for MFMA fragments
    const int nn  = ln & 15;   // row (A) / col (B,D) within 16-tile
    float* scr = sscr[wv];

    // ======== one-time staging (cross-wave; covered by the single barrier) ====
    if (tid < 16) sxp[256 * XSTR + tid] = 0.0f;           // NaN-proof tail
    for (int t = tid; t < E * D * H; t += 256) {          // eW1: 544
        swl[(t / 136) * WSTR + (t % 136)] = eW1[t];
    }
    if (tid < E * H * H) {                                 // eW2: 256
        swl[(tid / 64) * WSTR + 144 + (tid % 64)] = eW2[tid];
    }
    if (tid < E * H * OUT) {                               // eW3: 192, rows padded to 8
        int e = tid / 48, r = tid % 48, k = r / 6, o = r % 6;
        swl[e * WSTR + 216 + k * 8 + o] = eW3[tid];
    }
    if (tid < E * H) swl[(tid / 8) * WSTR + 136 + (tid % 8)] = eb1[tid];
    if (tid < E * H) swl[(tid / 8) * WSTR + 208 + (tid % 8)] = eb2[tid];
    if (tid < E * OUT) swl[(tid / 6) * WSTR + 280 + (tid % 6)] = eb3[tid];

    // stage chunk 0 of this wave's own 64-row stripe (wave-local, coalesced)
    {
        const float* gs = x + (long long)blockIdx.x * (CHUNKS * 256 * D) + wv * (64 * D);
        float* ls = &sxp[wv * (64 * D)];
        #pragma unroll
        for (int i = 0; i < D; ++i) ls[i * 64 + ln] = gs[i * 64 + ln];
    }

    // ======== hoist gating biases + B-fragments from GLOBAL into registers ====
    float cb1[4], cb2[2], cb3;
    #pragma unroll
    for (int ct = 0; ct < 4; ++ct) cb1[ct] = gb1[ct * 16 + nn];
    cb2[0] = gb2[nn]; cb2[1] = gb2[16 + nn];
    cb3 = (nn < 4) ? gb3[nn] : 0.0f;

    s16x8 B1h[4], B1l[4];          // k = g*8..+7; k>=17 zero; g==3 all-zero
    #pragma unroll
    for (int ct = 0; ct < 4; ++ct) {
        U4S8 Hh, Ll;
        #pragma unroll
        for (int j2 = 0; j2 < 4; ++j2) {
            const int k0 = g * 8 + 2 * j2, n = ct * 16 + nn;
            const float a = (k0 < D)     ? gW1[k0 * G1 + n]       : 0.0f;
            const float b = (k0 + 1 < D) ? gW1[(k0 + 1) * G1 + n] : 0.0f;
            wsplit2(a, b, Hh.u[j2], Ll.u[j2]);
        }
        B1h[ct] = Hh.s; B1l[ct] = Ll.s;
    }
    s16x8 B2h[2][2], B2l[2][2];    // k = kt*32 + g*8..+7 (all valid)
    #pragma unroll
    for (int ct = 0; ct < 2; ++ct)
        #pragma unroll
        for (int kt = 0; kt < 2; ++kt) {
            U4S8 Hh, Ll;
            #pragma unroll
            for (int j2 = 0; j2 < 4; ++j2) {
                const int k0 = kt * 32 + g * 8 + 2 * j2, n = ct * 16 + nn;
                wsplit2(gW2[k0 * G2 + n], gW2[(k0 + 1) * G2 + n], Hh.u[j2], Ll.u[j2]);
            }
            B2h[ct][kt] = Hh.s; B2l[ct][kt] = Ll.s;
        }
    s16x8 B3h, B3l;                // k = g*8..+7 (valid); cols nn>=4 zero
    {
        U4S8 Hh, Ll;
        #pragma unroll
        for (int j2 = 0; j2 < 4; ++j2) {
            const int k0 = g * 8 + 2 * j2;
            const float a = (nn < 4) ? gW3[k0 * E + nn]       : 0.0f;
            const float b = (nn < 4) ? gW3[(k0 + 1) * E + nn] : 0.0f;
            wsplit2(a, b, Hh.u[j2], Ll.u[j2]);
        }
        B3h = Hh.s; B3l = Ll.s;
    }

    __syncthreads();   // swl + tail visible; chunk-0 stripes all staged

    // ======== chunk loop: 4 chunks of 256 samples, NO per-chunk barriers ======
    // Each wave touches only its own sxp stripe + its own sscr region. The A1
    // over-read past a stripe boundary reads finite x floats (dword-atomic LDS)
    // times zero weights -> inert.
    #pragma unroll 1
    for (int c = 0; c < CHUNKS; ++c) {
        const long long cbase = ((long long)blockIdx.x * CHUNKS + c) * 256;
        if (c) {
            const float* gs = x + cbase * D + wv * (64 * D);
            float* ls = &sxp[wv * (64 * D)];
            #pragma unroll
            for (int i = 0; i < D; ++i) ls[i * 64 + ln] = gs[i * 64 + ln];
        }

        // ---- gating via MFMA (per-wave: 4 row-tiles of 16 samples) ----
        f32x4 Lg[4];
        #pragma unroll
        for (int rt = 0; rt < 4; ++rt) {
            const int srow = wv * 64 + rt * 16 + nn;
            // A1: 8 fp32; g==3 clamps to row start (finite x, zero B1 weights)
            float xv[8];
            const int xb = srow * XSTR + ((g == 3) ? 0 : g * 8);
            #pragma unroll
            for (int j = 0; j < 8; ++j) xv[j] = sxp[xb + j];
            s16x8 a1h, a1m, a1l; split8t(xv, a1h, a1m, a1l);

            // L1: 17->64, 4 col-tiles
            #pragma unroll
            for (int ct = 0; ct < 4; ++ct) {
                f32x4 d = {cb1[ct], cb1[ct], cb1[ct], cb1[ct]};
                MM5(d, a1h, a1m, a1l, B1h[ct], B1l[ct]);
                #pragma unroll
                for (int r = 0; r < 4; ++r) {
                    float hv = fmaxf(d[r], 0.0f);
                    int s = g * 4 + r, n = ct * 16 + nn;
                    scr[s * 64 + (((n >> 2) ^ (s & 15)) << 2) + (n & 3)] = hv;
                }
            }

            // A2 frags from h1
            s16x8 a2h[2], a2m[2], a2l[2];
            #pragma unroll
            for (int kt = 0; kt < 2; ++kt) {
                int kb0 = kt * 8 + g * 2;
                float hv8[8];
                *(f32x4*)&hv8[0] = *(const f32x4*)(&scr[nn * 64 + ((kb0 ^ (nn & 15)) << 2)]);
                *(f32x4*)&hv8[4] = *(const f32x4*)(&scr[nn * 64 + (((kb0 + 1) ^ (nn & 15)) << 2)]);
                split8t(hv8, a2h[kt], a2m[kt], a2l[kt]);
            }

            // L2: 64->32
            #pragma unroll
            for (int ct = 0; ct < 2; ++ct) {
                f32x4 d = {cb2[ct], cb2[ct], cb2[ct], cb2[ct]};
                #pragma unroll
                for (int kt = 0; kt < 2; ++kt) {
                    MM5(d, a2h[kt], a2m[kt], a2l[kt], B2h[ct][kt], B2l[ct][kt]);
                }
                #pragma unroll
                for (int r = 0; r < 4; ++r) {
                    float hv = fmaxf(d[r], 0.0f);
                    int s = g * 4 + r, n = ct * 16 + nn;
                    scr[s * 32 + (((n >> 2) ^ (s & 7)) << 2) + (n & 3)] = hv;
                }
            }

            // A3 frags from h2
            float h28[8];
            *(f32x4*)&h28[0] = *(const f32x4*)(&scr[nn * 32 + (((2 * g) ^ (nn & 7)) << 2)]);
            *(f32x4*)&h28[4] = *(const f32x4*)(&scr[nn * 32 + (((2 * g + 1) ^ (nn & 7)) << 2)]);
            s16x8 a3h, a3m, a3l; split8t(h28, a3h, a3m, a3l);

            // L3: 32->4
            f32x4 d3 = {cb3, cb3, cb3, cb3};
            MM5(d3, a3h, a3m, a3l, B3h, B3l);
            Lg[rt] = d3;
        }

        // ---- redistribute logits: D-layout -> one sample per lane ----
        if (nn < 4) {
            #pragma unroll
            for (int rt = 0; rt < 4; ++rt)
                #pragma unroll
                for (int r = 0; r < 4; ++r)
                    scr[(rt * 16 + g * 4 + r) * 4 + nn] = Lg[rt][r];
        }
        f32x4 lgv = *(const f32x4*)(&scr[ln * 4]);

        // ---- argmax (first-max-wins) + top-2 gap ----
        int sel = 0;
        {
            float b = lgv.x;
            if (lgv.y > b) { b = lgv.y; sel = 1; }
            if (lgv.z > b) { b = lgv.z; sel = 2; }
            if (lgv.w > b) { b = lgv.w; sel = 3; }
        }
        float mx01 = fmaxf(lgv.x, lgv.y), mn01 = fminf(lgv.x, lgv.y);
        float mx23 = fmaxf(lgv.z, lgv.w), mn23 = fminf(lgv.z, lgv.w);
        float best   = fmaxf(mx01, mx23);
        float second = fmaxf(fminf(mx01, mx23), (mx01 >= mx23) ? mn01 : mn23);

        // ---- rare exact-fp32 cooperative fallback for near-tie routing ----
        unsigned long long fmask = __ballot(best - second < GTHR);
        if (fmask) {
            do {
                int sl = (int)__builtin_ctzll(fmask);
                fmask &= (fmask - 1);
                const int fr = wv * 64 + sl;
                float h1j = gb1[ln];
                #pragma unroll 1
                for (int i = 0; i < D; ++i)
                    h1j = __builtin_fmaf(sxp[fr * XSTR + i], gW1[i * G1 + ln], h1j);
                scr[ln] = fmaxf(h1j, 0.0f);
                int j2 = ln & 31;
                float h2j = gb2[j2];
                #pragma unroll 4
                for (int c2 = 0; c2 < G1; ++c2)
                    h2j = __builtin_fmaf(scr[c2], gW2[c2 * G2 + j2], h2j);
                scr[64 + j2] = fmaxf(h2j, 0.0f);
                int e = ln & 3;
                float lge = gb3[e];
                #pragma unroll 4
                for (int jj = 0; jj < G2; ++jj)
                    lge = __builtin_fmaf(scr[64 + jj], gW3[jj * E + e], lge);
                float l0 = __shfl(lge, 0), l1 = __shfl(lge, 1);
                float l2 = __shfl(lge, 2), l3 = __shfl(lge, 3);
                int s2 = 0; float bb = l0;
                if (l1 > bb) { bb = l1; s2 = 1; }
                if (l2 > bb) { bb = l2; s2 = 2; }
                if (l3 > bb) { bb = l3; s2 = 3; }
                if (ln == sl) sel = s2;
            } while (fmask);
        }

        // ---- selected expert only; x read directly from own sxp row ----
        const float* xrow = &sxp[tid * XSTR];
        const float* wl = &swl[sel * WSTR];

        float t1[H];
        {
            f32x4 ba = *(const f32x4*)(wl + 136);
            f32x4 bb = *(const f32x4*)(wl + 140);
            t1[0]=ba.x; t1[1]=ba.y; t1[2]=ba.z; t1[3]=ba.w;
            t1[4]=bb.x; t1[5]=bb.y; t1[6]=bb.z; t1[7]=bb.w;
        }
        #pragma unroll
        for (int i = 0; i < D; ++i) {
            const float xi = xrow[i];
            f32x4 wa = *(const f32x4*)(wl + i * 8);
            f32x4 wb = *(const f32x4*)(wl + i * 8 + 4);
            t1[0] = __builtin_fmaf(xi, wa.x, t1[0]);
            t1[1] = __builtin_fmaf(xi, wa.y, t1[1]);
            t1[2] = __builtin_fmaf(xi, wa.z, t1[2]);
            t1[3] = __builtin_fmaf(xi, wa.w, t1[3]);
            t1[4] = __builtin_fmaf(xi, wb.x, t1[4]);
            t1[5] = __builtin_fmaf(xi, wb.y, t1[5]);
            t1[6] = __builtin_fmaf(xi, wb.z, t1[6]);
            t1[7] = __builtin_fmaf(xi, wb.w, t1[7]);
        }
        float t2[H];
        {
            f32x4 ba = *(const f32x4*)(wl + 208);
            f32x4 bb = *(const f32x4*)(wl + 212);
            t2[0]=ba.x; t2[1]=ba.y; t2[2]=ba.z; t2[3]=ba.w;
            t2[4]=bb.x; t2[5]=bb.y; t2[6]=bb.z; t2[7]=bb.w;
        }
        #pragma unroll
        for (int k = 0; k < H; ++k) {
            const float tv = fmaxf(t1[k], 0.0f);
            f32x4 wa = *(const f32x4*)(wl + 144 + k * 8);
            f32x4 wb = *(const f32x4*)(wl + 144 + k * 8 + 4);
            t2[0] = __builtin_fmaf(tv, wa.x, t2[0]);
            t2[1] = __builtin_fmaf(tv, wa.y, t2[1]);
            t2[2] = __builtin_fmaf(tv, wa.z, t2[2]);
            t2[3] = __builtin_fmaf(tv, wa.w, t2[3]);
            t2[4] = __builtin_fmaf(tv, wb.x, t2[4]);
            t2[5] = __builtin_fmaf(tv, wb.y, t2[5]);
            t2[6] = __builtin_fmaf(tv, wb.z, t2[6]);
            t2[7] = __builtin_fmaf(tv, wb.w, t2[7]);
        }
        float pred[OUT];
        {
            f32x4 ba = *(const f32x4*)(wl + 280);
            pred[0]=ba.x; pred[1]=ba.y; pred[2]=ba.z; pred[3]=ba.w;
            pred[4]=wl[284]; pred[5]=wl[285];
        }
        #pragma unroll
        for (int k = 0; k < H; ++k) {
            const float tv = fmaxf(t2[k], 0.0f);
            f32x4 wa = *(const f32x4*)(wl + 216 + k * 8);
            f32x2 wb = *(const f32x2*)(wl + 216 + k * 8 + 4);
            pred[0] = __builtin_fmaf(tv, wa.x, pred[0]);
            pred[1] = __builtin_fmaf(tv, wa.y, pred[1]);
            pred[2] = __builtin_fmaf(tv, wa.z, pred[2]);
            pred[3] = __builtin_fmaf(tv, wa.w, pred[3]);
            pred[4] = __builtin_fmaf(tv, wb.x, pred[4]);
            pred[5] = __builtin_fmaf(tv, wb.y, pred[5]);
        }

        // ---- stores ----
        const long long b = cbase + tid;
        f32x2 p0 = {pred[0], pred[1]};
        f32x2 p1 = {pred[2], pred[3]};
        f32x2 p2 = {pred[4], pred[5]};
        *(f32x2*)(out + b * 6)     = p0;
        *(f32x2*)(out + b * 6 + 2) = p1;
        *(f32x2*)(out + b * 6 + 4) = p2;
        float* lout = out + (long long)BTOT * OUT;
        *(f32x4*)(lout + b * 4) = lgv;
    }
}

extern "C" void kernel_launch(void* const* d_in, const int* in_sizes, int n_in,
                              void* d_out, int out_size, void* d_ws, size_t ws_size,
                              hipStream_t stream) {
    const float* x   = (const float*)d_in[0];
    const float* eW1 = (const float*)d_in[1];
    const float* eb1 = (const float*)d_in[2];
    const float* eW2 = (const float*)d_in[3];
    const float* eb2 = (const float*)d_in[4];
    const float* eW3 = (const float*)d_in[5];
    const float* eb3 = (const float*)d_in[6];
    const float* gW1 = (const float*)d_in[7];
    const float* gb1 = (const float*)d_in[8];
    const float* gW2 = (const float*)d_in[9];
    const float* gb2 = (const float*)d_in[10];
    const float* gW3 = (const float*)d_in[11];
    const float* gb3 = (const float*)d_in[12];
    float* out = (float*)d_out;

    dim3 grid(BTOT / (256 * CHUNKS)), block(256);
    hipLaunchKernelGGL(hybrid_ruc_kernel, grid, block, 0, stream,
                       x, eW1, eb1, eW2, eb2, eW3, eb3,
                       gW1, gb1, gW2, gb2, gW3, gb3, out);
}